// Round 1
// baseline (447.347 us; speedup 1.0000x reference)
//
#include <hip/hip_runtime.h>

typedef unsigned short u16;
typedef unsigned int   u32;
typedef __attribute__((ext_vector_type(8))) short s16x8;
typedef __attribute__((ext_vector_type(4))) float f32x4;

#define D_MODEL 1024
#define S_LEN   2048
#define BATCH   4
#define HEADS   16
#define DK      64
#define M_TOTAL (BATCH * S_LEN)   // 8192

__device__ __forceinline__ u16 f2b(float f) {
  u32 u = __float_as_uint(f);
  u32 r = u + 0x7FFFu + ((u >> 16) & 1u);
  return (u16)(r >> 16);
}
__device__ __forceinline__ float b2f(u16 b) {
  return __uint_as_float(((u32)b) << 16);
}

// ---------------- fp32 -> bf16 convert, 4 elems/thread ----------------
__global__ void k_f2bf(const float* __restrict__ in, u16* __restrict__ out, int n4) {
  int i = blockIdx.x * blockDim.x + threadIdx.x;
  if (i >= n4) return;
  float4 v = ((const float4*)in)[i];
  u32 lo = (u32)f2b(v.x) | ((u32)f2b(v.y) << 16);
  u32 hi = (u32)f2b(v.z) | ((u32)f2b(v.w) << 16);
  ((u32*)out)[2*i]   = lo;
  ((u32*)out)[2*i+1] = hi;
}

// ---------------- in-place RoPE on bf16 [M_TOTAL, D_MODEL], pair/thread ----
__global__ void k_rope(u16* __restrict__ Y, float scale) {
  int gid = blockIdx.x * blockDim.x + threadIdx.x;   // M_TOTAL*512 threads
  int m = gid >> 9;          // row (b*S + s)
  int p = gid & 511;         // pair index in row
  int s = m & (S_LEN - 1);
  int i = p & 31;            // freq index within head
  u32 v = ((u32*)Y)[(m << 9) + p];
  float x1 = b2f((u16)(v & 0xFFFFu));
  float x2 = b2f((u16)(v >> 16));
  // inv_freq = 10000^(-i/32) = exp(-i * ln(10000)/32)
  float inv = __expf(-(float)i * 0.28782313662425575f);
  float ang = (float)s * inv;
  float sn, cs;
  __sincosf(ang, &sn, &cs);
  float o1 = (x1 * cs - x2 * sn) * scale;
  float o2 = (x1 * sn + x2 * cs) * scale;
  ((u32*)Y)[(m << 9) + p] = (u32)f2b(o1) | ((u32)f2b(o2) << 16);
}

// ---------------- GEMM: C[m][n] = sum_k A[m][k] * B[n][k]  (both K-major bf16)
// 128x128 tile, BK=32, 4 waves (2x2), each wave 64x64 via 4x4 16x16x32 MFMA.
#define LDK 48  // padded LDS leading dim (16B-aligned rows, breaks pow2 stride)
template<bool BF16OUT>
__launch_bounds__(256, 2)
__global__ void k_gemm_bt(const u16* __restrict__ A, const u16* __restrict__ B,
                          void* __restrict__ C, int M, int N, int K) {
  __shared__ u16 Al[128 * LDK];
  __shared__ u16 Bl[128 * LDK];
  const int tid  = threadIdx.x;
  const int lane = tid & 63;
  const int w    = tid >> 6;
  const int wm   = (w >> 1) * 64, wn = (w & 1) * 64;
  const int bm   = blockIdx.y * 128, bn = blockIdx.x * 128;
  const int row  = lane & 15, q = lane >> 4;

  f32x4 acc[4][4];
#pragma unroll
  for (int i = 0; i < 4; i++)
#pragma unroll
    for (int j = 0; j < 4; j++) acc[i][j] = (f32x4){0.f, 0.f, 0.f, 0.f};

  const int r0 = tid >> 2;          // 0..63
  const int c0 = (tid & 3) * 8;     // 0,8,16,24
  const u16* Ag = A + (size_t)(bm + r0) * K + c0;
  const u16* Bg = B + (size_t)(bn + r0) * K + c0;

  for (int k0 = 0; k0 < K; k0 += 32) {
    uint4 a0 = *(const uint4*)(Ag + k0);
    uint4 a1 = *(const uint4*)(Ag + (size_t)64 * K + k0);
    uint4 b0 = *(const uint4*)(Bg + k0);
    uint4 b1 = *(const uint4*)(Bg + (size_t)64 * K + k0);
    __syncthreads();
    *(uint4*)(Al + r0 * LDK + c0)        = a0;
    *(uint4*)(Al + (r0 + 64) * LDK + c0) = a1;
    *(uint4*)(Bl + r0 * LDK + c0)        = b0;
    *(uint4*)(Bl + (r0 + 64) * LDK + c0) = b1;
    __syncthreads();
    s16x8 af[4], bfr[4];
#pragma unroll
    for (int mi = 0; mi < 4; mi++)
      af[mi] = *(const s16x8*)(Al + (wm + mi * 16 + row) * LDK + q * 8);
#pragma unroll
    for (int ni = 0; ni < 4; ni++)
      bfr[ni] = *(const s16x8*)(Bl + (wn + ni * 16 + row) * LDK + q * 8);
#pragma unroll
    for (int mi = 0; mi < 4; mi++)
#pragma unroll
      for (int ni = 0; ni < 4; ni++)
        acc[mi][ni] = __builtin_amdgcn_mfma_f32_16x16x32_bf16(af[mi], bfr[ni], acc[mi][ni], 0, 0, 0);
  }

#pragma unroll
  for (int mi = 0; mi < 4; mi++)
#pragma unroll
    for (int ni = 0; ni < 4; ni++)
#pragma unroll
      for (int r = 0; r < 4; r++) {
        int grow = bm + wm + mi * 16 + q * 4 + r;
        int gcol = bn + wn + ni * 16 + row;
        float v = acc[mi][ni][r];
        if (BF16OUT) ((u16*)C)[(size_t)grow * N + gcol] = f2b(v);
        else         ((float*)C)[(size_t)grow * N + gcol] = v;
      }
}

// ---------------- flash attention (causal), bf16 in, bf16 out --------------
// grid: (S/64, HEADS, BATCH); 256 threads = 4 waves; wave w: q-rows [q0+16w, +16)
__launch_bounds__(256, 2)
__global__ void k_attn(const u16* __restrict__ Qb, const u16* __restrict__ Kb,
                       const u16* __restrict__ Vb, u16* __restrict__ Mh) {
  __shared__ u16 Kl[128 * 72];       // K-tile [key][dk], padded
  __shared__ u16 Vt[64 * 136];       // V-tile transposed [dk][key], padded
  __shared__ u16 Pl[4 * 16 * 136];   // per-wave P scratch [16][136]
  const int tid  = threadIdx.x;
  const int lane = tid & 63;
  const int w    = tid >> 6;
  const int row  = lane & 15, q = lane >> 4;
  const int qt = blockIdx.x, h = blockIdx.y, b = blockIdx.z;
  const int q0 = qt * 64;
  const size_t base = ((size_t)b * S_LEN) * D_MODEL + (size_t)h * DK;

  // Q fragments (rows q0 + w*16 + row), Q pre-scaled by 1/sqrt(dk)
  s16x8 aq[2];
  {
    size_t qoff = base + (size_t)(q0 + w * 16 + row) * D_MODEL + q * 8;
    aq[0] = *(const s16x8*)(Qb + qoff);
    aq[1] = *(const s16x8*)(Qb + qoff + 32);
  }

  f32x4 o[4];
#pragma unroll
  for (int di = 0; di < 4; di++) o[di] = (f32x4){0.f, 0.f, 0.f, 0.f};
  float mrow[4], lrow[4];
#pragma unroll
  for (int r = 0; r < 4; r++) { mrow[r] = -3.0e38f; lrow[r] = 0.f; }

  const int pbase = w * 16 * 136;

  for (int k0 = 0; k0 <= q0 + 63; k0 += 128) {
    // ---- stage K tile [128][64] ----
    int kr = tid >> 2;
    int kc = (tid & 3) * 8;
    uint4 v00 = *(const uint4*)(Kb + base + (size_t)(k0 + kr) * D_MODEL + kc);
    uint4 v01 = *(const uint4*)(Kb + base + (size_t)(k0 + kr) * D_MODEL + kc + 32);
    uint4 v10 = *(const uint4*)(Kb + base + (size_t)(k0 + kr + 64) * D_MODEL + kc);
    uint4 v11 = *(const uint4*)(Kb + base + (size_t)(k0 + kr + 64) * D_MODEL + kc + 32);
    // ---- stage V tile transposed ----
    int vr  = tid >> 1;            // key row 0..127
    int vc0 = (tid & 1) * 32;      // dk chunk base
    uint4 vv[4];
#pragma unroll
    for (int i = 0; i < 4; i++)
      vv[i] = *(const uint4*)(Vb + base + (size_t)(k0 + vr) * D_MODEL + vc0 + i * 8);
    __syncthreads();   // previous iteration's K/V reads are done
    *(uint4*)(Kl + kr * 72 + kc)             = v00;
    *(uint4*)(Kl + kr * 72 + kc + 32)        = v01;
    *(uint4*)(Kl + (kr + 64) * 72 + kc)      = v10;
    *(uint4*)(Kl + (kr + 64) * 72 + kc + 32) = v11;
#pragma unroll
    for (int i = 0; i < 4; i++) {
      u16 tmp[8];
      *(uint4*)tmp = vv[i];
      int dk0 = vc0 + i * 8;
#pragma unroll
      for (int j = 0; j < 8; j++) Vt[(dk0 + j) * 136 + vr] = tmp[j];
    }
    __syncthreads();

    // ---- S = Q K^T (pre-scaled) ----
    f32x4 sf[8];
#pragma unroll
    for (int ni = 0; ni < 8; ni++) {
      sf[ni] = (f32x4){0.f, 0.f, 0.f, 0.f};
      s16x8 b0 = *(const s16x8*)(Kl + (ni * 16 + row) * 72 + q * 8);
      s16x8 b1 = *(const s16x8*)(Kl + (ni * 16 + row) * 72 + 32 + q * 8);
      sf[ni] = __builtin_amdgcn_mfma_f32_16x16x32_bf16(aq[0], b0, sf[ni], 0, 0, 0);
      sf[ni] = __builtin_amdgcn_mfma_f32_16x16x32_bf16(aq[1], b1, sf[ni], 0, 0, 0);
    }

    // ---- causal mask + row max ----
    const int srbase = q0 + w * 16 + q * 4;
    float rm[4];
#pragma unroll
    for (int r = 0; r < 4; r++) rm[r] = -3.0e38f;
#pragma unroll
    for (int ni = 0; ni < 8; ni++)
#pragma unroll
      for (int r = 0; r < 4; r++) {
        int col = k0 + ni * 16 + row;
        float v = sf[ni][r];
        v = (col <= srbase + r) ? v : -3.0e38f;
        sf[ni][r] = v;
        rm[r] = fmaxf(rm[r], v);
      }
#pragma unroll
    for (int r = 0; r < 4; r++) {
      rm[r] = fmaxf(rm[r], __shfl_xor(rm[r], 1));
      rm[r] = fmaxf(rm[r], __shfl_xor(rm[r], 2));
      rm[r] = fmaxf(rm[r], __shfl_xor(rm[r], 4));
      rm[r] = fmaxf(rm[r], __shfl_xor(rm[r], 8));
    }
    float alpha[4], rs[4];
#pragma unroll
    for (int r = 0; r < 4; r++) {
      float mn = fmaxf(mrow[r], rm[r]);
      alpha[r] = __expf(mrow[r] - mn);
      mrow[r] = mn;
      rs[r] = 0.f;
    }
    // ---- P = exp(S - m), stash to LDS (C-layout -> A-layout round trip) ----
#pragma unroll
    for (int ni = 0; ni < 8; ni++)
#pragma unroll
      for (int r = 0; r < 4; r++) {
        float p = __expf(sf[ni][r] - mrow[r]);
        rs[r] += p;
        Pl[pbase + (q * 4 + r) * 136 + ni * 16 + row] = f2b(p);
      }
#pragma unroll
    for (int r = 0; r < 4; r++) {
      rs[r] += __shfl_xor(rs[r], 1);
      rs[r] += __shfl_xor(rs[r], 2);
      rs[r] += __shfl_xor(rs[r], 4);
      rs[r] += __shfl_xor(rs[r], 8);
      lrow[r] = lrow[r] * alpha[r] + rs[r];
    }
    // ---- rescale O, then O += P V ----
#pragma unroll
    for (int di = 0; di < 4; di++)
#pragma unroll
      for (int r = 0; r < 4; r++) o[di][r] *= alpha[r];
#pragma unroll
    for (int kk2 = 0; kk2 < 4; kk2++) {
      s16x8 pf = *(const s16x8*)(Pl + pbase + row * 136 + kk2 * 32 + q * 8);
#pragma unroll
      for (int di = 0; di < 4; di++) {
        s16x8 vf = *(const s16x8*)(Vt + (di * 16 + row) * 136 + kk2 * 32 + q * 8);
        o[di] = __builtin_amdgcn_mfma_f32_16x16x32_bf16(pf, vf, o[di], 0, 0, 0);
      }
    }
  }

  // ---- epilogue: O / l -> Mh (bf16, [B*S, D_MODEL] layout) ----
#pragma unroll
  for (int di = 0; di < 4; di++)
#pragma unroll
    for (int r = 0; r < 4; r++) {
      float v = o[di][r] / lrow[r];
      int m = q0 + w * 16 + q * 4 + r;
      Mh[((size_t)b * S_LEN + m) * D_MODEL + h * DK + di * 16 + row] = f2b(v);
    }
}

extern "C" void kernel_launch(void* const* d_in, const int* in_sizes, int n_in,
                              void* d_out, int out_size, void* d_ws, size_t ws_size,
                              hipStream_t stream) {
  const float* x  = (const float*)d_in[0];
  const float* Wq = (const float*)d_in[1];
  const float* Wk = (const float*)d_in[2];
  const float* Wv = (const float*)d_in[3];
  const float* Wo = (const float*)d_in[4];
  float* out = (float*)d_out;

  char* ws = (char*)d_ws;
  const size_t xsz = (size_t)M_TOTAL * D_MODEL * 2;   // bf16 activation tensor
  const size_t wsz = (size_t)D_MODEL * D_MODEL * 2;   // bf16 weight tensor
  u16* Xb  = (u16*)ws; ws += xsz;
  u16* Wqb = (u16*)ws; ws += wsz;
  u16* Wkb = (u16*)ws; ws += wsz;
  u16* Wvb = (u16*)ws; ws += wsz;
  u16* Wob = (u16*)ws; ws += wsz;
  u16* Qb  = (u16*)ws; ws += xsz;
  u16* Kb  = (u16*)ws; ws += xsz;
  u16* Vb  = (u16*)ws; ws += xsz;
  u16* Mh  = (u16*)ws; ws += xsz;

  // converts
  {
    int n4 = M_TOTAL * D_MODEL / 4;
    k_f2bf<<<(n4 + 255) / 256, 256, 0, stream>>>(x, Xb, n4);
    n4 = D_MODEL * D_MODEL / 4;
    int blk = (n4 + 255) / 256;
    k_f2bf<<<blk, 256, 0, stream>>>(Wq, Wqb, n4);
    k_f2bf<<<blk, 256, 0, stream>>>(Wk, Wkb, n4);
    k_f2bf<<<blk, 256, 0, stream>>>(Wv, Wvb, n4);
    k_f2bf<<<blk, 256, 0, stream>>>(Wo, Wob, n4);
  }
  // projections
  dim3 gg(D_MODEL / 128, M_TOTAL / 128);
  k_gemm_bt<true><<<gg, 256, 0, stream>>>(Xb, Wqb, Qb, M_TOTAL, D_MODEL, D_MODEL);
  k_gemm_bt<true><<<gg, 256, 0, stream>>>(Xb, Wkb, Kb, M_TOTAL, D_MODEL, D_MODEL);
  k_gemm_bt<true><<<gg, 256, 0, stream>>>(Xb, Wvb, Vb, M_TOTAL, D_MODEL, D_MODEL);
  // RoPE (Q also folds 1/sqrt(dk) = 0.125)
  {
    int nthreads = M_TOTAL * 512;
    k_rope<<<nthreads / 256, 256, 0, stream>>>(Qb, 0.125f);
    k_rope<<<nthreads / 256, 256, 0, stream>>>(Kb, 1.0f);
  }
  // attention
  dim3 ga(S_LEN / 64, HEADS, BATCH);
  k_attn<<<ga, 256, 0, stream>>>(Qb, Kb, Vb, Mh);
  // output projection (fp32 out)
  k_gemm_bt<false><<<gg, 256, 0, stream>>>(Mh, Wob, out, M_TOTAL, D_MODEL, D_MODEL);
}

// Round 2
// 422.049 us; speedup vs baseline: 1.0599x; 1.0599x over previous
//
#include <hip/hip_runtime.h>

typedef unsigned short u16;
typedef unsigned int   u32;
typedef __attribute__((ext_vector_type(8))) short s16x8;
typedef __attribute__((ext_vector_type(4))) float f32x4;

#define D_MODEL 1024
#define S_LEN   2048
#define BATCH   4
#define HEADS   16
#define DK      64
#define M_TOTAL (BATCH * S_LEN)   // 8192

// Q scale: 1/sqrt(64) * log2(e)  (scores produced in log2 domain for exp2)
#define QSCALE 0.18033688011112042f
// log2(10000)/32
#define ROPE_L2 0.41524101186092029f

__device__ __forceinline__ u16 f2b(float f) {
  u32 u = __float_as_uint(f);
  u32 r = u + 0x7FFFu + ((u >> 16) & 1u);
  return (u16)(r >> 16);
}

typedef const __attribute__((address_space(1))) unsigned int* gas_u32p;
typedef __attribute__((address_space(3))) unsigned int* las_u32p;
#define GLL16(gp, lp) __builtin_amdgcn_global_load_lds((gas_u32p)(gp), (las_u32p)(lp), 16, 0, 0)

// ---------------- fp32 -> bf16 convert, 4 elems/thread ----------------
__global__ void k_f2bf(const float* __restrict__ in, u16* __restrict__ out, int n4) {
  int i = blockIdx.x * blockDim.x + threadIdx.x;
  if (i >= n4) return;
  float4 v = ((const float4*)in)[i];
  u32 lo = (u32)f2b(v.x) | ((u32)f2b(v.y) << 16);
  u32 hi = (u32)f2b(v.z) | ((u32)f2b(v.w) << 16);
  ((u32*)out)[2*i]   = lo;
  ((u32*)out)[2*i+1] = hi;
}

// ---------------- GEMM: C[m][n] = sum_k A[m][k] * B[n][k]  (both K-major bf16)
// m97 recipe: 128x128 tile, BK=32, unpadded LDS, global_load_lds width 16.
// Optional fused RoPE (+scale) epilogue for Q/K projections.
template<bool BF16OUT, bool ROPE>
__launch_bounds__(256, 4)
__global__ void k_gemm(const u16* __restrict__ A, const u16* __restrict__ B,
                       void* __restrict__ C, int M, int N, int K, float scale) {
  __shared__ u16 Al[128 * 32];
  __shared__ u16 Bl[128 * 32];
  const int tid  = threadIdx.x;
  const int lane = tid & 63;
  const int w    = tid >> 6;
  const int wm   = (w >> 1) * 64, wn = (w & 1) * 64;
  const int bm   = blockIdx.y * 128, bn = blockIdx.x * 128;
  const int row  = lane & 15, q = lane >> 4;

  f32x4 acc[4][4];
#pragma unroll
  for (int i = 0; i < 4; i++)
#pragma unroll
    for (int j = 0; j < 4; j++) acc[i][j] = (f32x4){0.f, 0.f, 0.f, 0.f};

  // global_load_lds: per-instruction, wave covers 16 rows x 64B (lane i ->
  // row (i>>2), 16B chunk (i&3)); LDS dest = uniform base + lane*16.
  const int r16 = lane >> 2;
  const int cb  = (lane & 3) * 8;
  const u16* Ag0 = A + (size_t)(bm + w * 32 + r16) * K + cb;
  const u16* Ag1 = Ag0 + (size_t)16 * K;
  const u16* Bg0 = B + (size_t)(bn + w * 32 + r16) * K + cb;
  const u16* Bg1 = Bg0 + (size_t)16 * K;
  u16* Ad0 = Al + (w * 32) * 32;
  u16* Ad1 = Al + (w * 32 + 16) * 32;
  u16* Bd0 = Bl + (w * 32) * 32;
  u16* Bd1 = Bl + (w * 32 + 16) * 32;

  for (int k0 = 0; k0 < K; k0 += 32) {
    __syncthreads();
    GLL16(Ag0 + k0, Ad0);
    GLL16(Ag1 + k0, Ad1);
    GLL16(Bg0 + k0, Bd0);
    GLL16(Bg1 + k0, Bd1);
    __syncthreads();   // drains vmcnt -> LDS staging complete
    s16x8 af[4], bfr[4];
#pragma unroll
    for (int mi = 0; mi < 4; mi++)
      af[mi] = *(const s16x8*)(Al + (wm + mi * 16 + row) * 32 + q * 8);
#pragma unroll
    for (int ni = 0; ni < 4; ni++)
      bfr[ni] = *(const s16x8*)(Bl + (wn + ni * 16 + row) * 32 + q * 8);
#pragma unroll
    for (int mi = 0; mi < 4; mi++)
#pragma unroll
      for (int ni = 0; ni < 4; ni++)
        acc[mi][ni] = __builtin_amdgcn_mfma_f32_16x16x32_bf16(af[mi], bfr[ni], acc[mi][ni], 0, 0, 0);
  }

#pragma unroll
  for (int mi = 0; mi < 4; mi++)
#pragma unroll
    for (int ni = 0; ni < 4; ni++) {
      if (ROPE) {
        // cols pair (even,odd) within a head; pairs live in adjacent lanes.
        const int col = bn + wn + ni * 16 + row;
        const int fi  = (col & 63) >> 1;
        const float inv = exp2f(-(float)fi * ROPE_L2);
        const bool odd = (row & 1);
#pragma unroll
        for (int r = 0; r < 4; r++) {
          int grow = bm + wm + mi * 16 + q * 4 + r;
          float own = acc[mi][ni][r];
          float oth = __shfl_xor(own, 1);
          float ang = (float)(grow & (S_LEN - 1)) * inv;
          float sn, cs;
          __sincosf(ang, &sn, &cs);
          float x1 = odd ? oth : own;
          float x2 = odd ? own : oth;
          float res = odd ? (x1 * sn + x2 * cs) : (x1 * cs - x2 * sn);
          acc[mi][ni][r] = res * scale;
        }
      }
#pragma unroll
      for (int r = 0; r < 4; r++) {
        int grow = bm + wm + mi * 16 + q * 4 + r;
        int gcol = bn + wn + ni * 16 + row;
        float v = acc[mi][ni][r];
        if (BF16OUT) ((u16*)C)[(size_t)grow * N + gcol] = f2b(v);
        else         ((float*)C)[(size_t)grow * N + gcol] = v;
      }
    }
}

// ---------------- flash attention (causal), fixed-max exp2 softmax ---------
// grid: (S/128, HEADS, BATCH) with qt reversed for big-blocks-first dispatch.
// 256 threads = 4 waves; wave w owns 32 q-rows (2 m-tiles of 16).
// V comes pre-transposed: Vtg[h*64+dk][b*2048+s].
__launch_bounds__(256, 3)
__global__ void k_attn(const u16* __restrict__ Qb, const u16* __restrict__ Kb,
                       const u16* __restrict__ Vtg, u16* __restrict__ Mh) {
  __shared__ u16 Kl[128 * 72];       // K-tile [key][dk], stride 72 (16B-aligned rows)
  __shared__ u16 Vt[64 * 136];       // V^T tile [dk][key], stride 136
  __shared__ u16 Pl[4 * 16 * 136];   // per-wave P scratch [16 qrow][keys]
  const int tid  = threadIdx.x;
  const int lane = tid & 63;
  const int w    = tid >> 6;
  const int row  = lane & 15, q = lane >> 4;
  const int qt = (int)gridDim.x - 1 - (int)blockIdx.x;
  const int h = blockIdx.y, b = blockIdx.z;
  const int q0 = qt * 128;
  const size_t kbase = ((size_t)b * S_LEN) * D_MODEL + (size_t)h * DK;
  const size_t vbase = ((size_t)h * DK) * M_TOTAL + (size_t)b * S_LEN;

  // Q fragments: wave w, m-tile mi -> rows q0 + w*32 + mi*16 + row
  s16x8 aq[2][2];
#pragma unroll
  for (int mi = 0; mi < 2; mi++) {
    size_t qoff = kbase + (size_t)(q0 + w * 32 + mi * 16 + row) * D_MODEL + q * 8;
    aq[mi][0] = *(const s16x8*)(Qb + qoff);
    aq[mi][1] = *(const s16x8*)(Qb + qoff + 32);
  }

  f32x4 o[2][4];
#pragma unroll
  for (int mi = 0; mi < 2; mi++)
#pragma unroll
    for (int di = 0; di < 4; di++) o[mi][di] = (f32x4){0.f, 0.f, 0.f, 0.f};
  float lacc[2][4];
#pragma unroll
  for (int mi = 0; mi < 2; mi++)
#pragma unroll
    for (int r = 0; r < 4; r++) lacc[mi][r] = 0.f;

  uint4 gk[4], gv[4];
  // prologue loads for tile 0
#pragma unroll
  for (int p = 0; p < 4; p++) {
    int idx = p * 256 + tid;
    gk[p] = *(const uint4*)(Kb + kbase + (size_t)(idx >> 3) * D_MODEL + (idx & 7) * 8);
    gv[p] = *(const uint4*)(Vtg + vbase + (size_t)(idx >> 4) * M_TOTAL + (idx & 15) * 8);
  }

  const int ktiles = qt + 1;
  for (int t = 0; t < ktiles; t++) {
    const int k0 = t * 128;
    __syncthreads();   // previous iteration's LDS reads done
#pragma unroll
    for (int p = 0; p < 4; p++) {
      int idx = p * 256 + tid;
      *(uint4*)(Kl + (idx >> 3) * 72 + (idx & 7) * 8) = gk[p];
      *(uint4*)(Vt + (idx >> 4) * 136 + (idx & 15) * 8) = gv[p];
    }
    __syncthreads();
    if (t + 1 < ktiles) {
      const int kn = k0 + 128;
#pragma unroll
      for (int p = 0; p < 4; p++) {
        int idx = p * 256 + tid;
        gk[p] = *(const uint4*)(Kb + kbase + (size_t)(kn + (idx >> 3)) * D_MODEL + (idx & 7) * 8);
        gv[p] = *(const uint4*)(Vtg + vbase + (size_t)(idx >> 4) * M_TOTAL + kn + (idx & 15) * 8);
      }
    }

#pragma unroll
    for (int mi = 0; mi < 2; mi++) {
      const int rb = q0 + w * 32 + mi * 16;   // wave-uniform base q-row
      // ---- S^ = Q K^T (log2 domain, pre-scaled) ----
      f32x4 sf[8];
#pragma unroll
      for (int nt = 0; nt < 8; nt++) {
        sf[nt] = (f32x4){0.f, 0.f, 0.f, 0.f};
        s16x8 b0 = *(const s16x8*)(Kl + (nt * 16 + row) * 72 + q * 8);
        s16x8 b1 = *(const s16x8*)(Kl + (nt * 16 + row) * 72 + 32 + q * 8);
        sf[nt] = __builtin_amdgcn_mfma_f32_16x16x32_bf16(aq[mi][0], b0, sf[nt], 0, 0, 0);
        sf[nt] = __builtin_amdgcn_mfma_f32_16x16x32_bf16(aq[mi][1], b1, sf[nt], 0, 0, 0);
      }
      // ---- P = exp2(S^), causal mask only on diagonal tiles ----
      const bool needmask = (k0 + 127) > rb;   // wave-uniform branch
      if (needmask) {
#pragma unroll
        for (int nt = 0; nt < 8; nt++)
#pragma unroll
          for (int r = 0; r < 4; r++) {
            int key = k0 + nt * 16 + row;
            float v = (key <= rb + q * 4 + r) ? sf[nt][r] : -1e30f;
            float p = exp2f(v);
            lacc[mi][r] += p;
            Pl[(w * 16 + q * 4 + r) * 136 + nt * 16 + row] = f2b(p);
          }
      } else {
#pragma unroll
        for (int nt = 0; nt < 8; nt++)
#pragma unroll
          for (int r = 0; r < 4; r++) {
            float p = exp2f(sf[nt][r]);
            lacc[mi][r] += p;
            Pl[(w * 16 + q * 4 + r) * 136 + nt * 16 + row] = f2b(p);
          }
      }
      // ---- O += P V  (P re-read in A-layout from per-wave LDS region) ----
#pragma unroll
      for (int kk = 0; kk < 4; kk++) {
        s16x8 pf = *(const s16x8*)(Pl + (w * 16 + row) * 136 + kk * 32 + q * 8);
#pragma unroll
        for (int di = 0; di < 4; di++) {
          s16x8 vf = *(const s16x8*)(Vt + (di * 16 + row) * 136 + kk * 32 + q * 8);
          o[mi][di] = __builtin_amdgcn_mfma_f32_16x16x32_bf16(pf, vf, o[mi][di], 0, 0, 0);
        }
      }
    }
  }

  // ---- epilogue: single deferred l-reduction, then O/l -> Mh ----
#pragma unroll
  for (int mi = 0; mi < 2; mi++) {
    float linv[4];
#pragma unroll
    for (int r = 0; r < 4; r++) {
      float l = lacc[mi][r];
      l += __shfl_xor(l, 1);
      l += __shfl_xor(l, 2);
      l += __shfl_xor(l, 4);
      l += __shfl_xor(l, 8);
      linv[r] = 1.0f / l;
    }
#pragma unroll
    for (int di = 0; di < 4; di++)
#pragma unroll
      for (int r = 0; r < 4; r++) {
        int qrow = q0 + w * 32 + mi * 16 + q * 4 + r;
        int dk = di * 16 + row;
        Mh[((size_t)b * S_LEN + qrow) * D_MODEL + h * DK + dk] = f2b(o[mi][di][r] * linv[r]);
      }
  }
}

extern "C" void kernel_launch(void* const* d_in, const int* in_sizes, int n_in,
                              void* d_out, int out_size, void* d_ws, size_t ws_size,
                              hipStream_t stream) {
  const float* x  = (const float*)d_in[0];
  const float* Wq = (const float*)d_in[1];
  const float* Wk = (const float*)d_in[2];
  const float* Wv = (const float*)d_in[3];
  const float* Wo = (const float*)d_in[4];
  float* out = (float*)d_out;

  char* ws = (char*)d_ws;
  const size_t xsz = (size_t)M_TOTAL * D_MODEL * 2;
  const size_t wsz = (size_t)D_MODEL * D_MODEL * 2;
  u16* Xb  = (u16*)ws; ws += xsz;
  u16* Wqb = (u16*)ws; ws += wsz;
  u16* Wkb = (u16*)ws; ws += wsz;
  u16* Wvb = (u16*)ws; ws += wsz;
  u16* Wob = (u16*)ws; ws += wsz;
  u16* Qb  = (u16*)ws; ws += xsz;
  u16* Kb  = (u16*)ws; ws += xsz;
  u16* Vtg = (u16*)ws; ws += xsz;   // V transposed: [1024][8192]
  u16* Mh  = (u16*)ws; ws += xsz;

  {
    int n4 = M_TOTAL * D_MODEL / 4;
    k_f2bf<<<(n4 + 255) / 256, 256, 0, stream>>>(x, Xb, n4);
    n4 = D_MODEL * D_MODEL / 4;
    int blk = (n4 + 255) / 256;
    k_f2bf<<<blk, 256, 0, stream>>>(Wq, Wqb, n4);
    k_f2bf<<<blk, 256, 0, stream>>>(Wk, Wkb, n4);
    k_f2bf<<<blk, 256, 0, stream>>>(Wv, Wvb, n4);
    k_f2bf<<<blk, 256, 0, stream>>>(Wo, Wob, n4);
  }

  // Q/K projections with fused RoPE (Q also folds 1/8 * log2e)
  dim3 gg(D_MODEL / 128, M_TOTAL / 128);
  k_gemm<true, true><<<gg, 256, 0, stream>>>(Xb, Wqb, Qb, M_TOTAL, D_MODEL, D_MODEL, QSCALE);
  k_gemm<true, true><<<gg, 256, 0, stream>>>(Xb, Wkb, Kb, M_TOTAL, D_MODEL, D_MODEL, 1.0f);
  // V projection computed TRANSPOSED: Vtg[e][bs] = sum_k Wv[e][k] X[bs][k]
  dim3 gv(M_TOTAL / 128, D_MODEL / 128);
  k_gemm<true, false><<<gv, 256, 0, stream>>>(Wvb, Xb, Vtg, D_MODEL, M_TOTAL, D_MODEL, 1.0f);

  dim3 ga(S_LEN / 128, HEADS, BATCH);
  k_attn<<<ga, 256, 0, stream>>>(Qb, Kb, Vtg, Mh);

  k_gemm<false, false><<<gg, 256, 0, stream>>>(Mh, Wob, out, M_TOTAL, D_MODEL, D_MODEL, 1.0f);
}